// Round 10
// baseline (158.783 us; speedup 1.0000x reference)
//
#include <hip/hip_runtime.h>
#include <math.h>

typedef unsigned short ushort_t;
typedef unsigned int uint_t;
typedef __attribute__((ext_vector_type(8))) short short8v;       // 8 bf16 = 4 VGPR
typedef __attribute__((ext_vector_type(4))) float float4v;       // MFMA accum
typedef __attribute__((ext_vector_type(4))) unsigned short ushort4v; // 8B load

static __device__ __forceinline__ ushort_t f2bf(float f) {
    union { float f; uint_t u; } v; v.f = f;
    uint_t r = (v.u + 0x7FFFu + ((v.u >> 16) & 1u)) >> 16;       // RNE
    return (ushort_t)r;
}
static __device__ __forceinline__ float bf2f(ushort_t u) {
    union { uint_t u; float f; } v; v.u = ((uint_t)u) << 16;
    return v.f;
}

// ---------------------------------------------------------------------------
// K0: convert fc1w (128x3136 fp32) -> bf16 in ws. 196 blocks x 256 thr x 8.
// ---------------------------------------------------------------------------
__global__ __launch_bounds__(256) void k_cvtw(
    const float* __restrict__ w, ushort_t* __restrict__ o)
{
    const int i = (blockIdx.x*256 + threadIdx.x) * 8;
    const float4 a = *(const float4*)(w + i);
    const float4 b = *(const float4*)(w + i + 4);
    short8v pk;
    pk[0]=(short)f2bf(a.x); pk[1]=(short)f2bf(a.y);
    pk[2]=(short)f2bf(a.z); pk[3]=(short)f2bf(a.w);
    pk[4]=(short)f2bf(b.x); pk[5]=(short)f2bf(b.y);
    pk[6]=(short)f2bf(b.z); pk[7]=(short)f2bf(b.w);
    *(short8v*)(o + i) = pk;
}

// ---------------------------------------------------------------------------
// Fully fused QFNN forward, ONE block (256 thr) per image. Round 10:
// = round 9 (conv2 via bf16 MFMA), fc1 now reads bf16 weights from ws
// (half the L2 stream). Fallback fp32-weight path if fc1wb == nullptr.
// ---------------------------------------------------------------------------
__global__ __launch_bounds__(256) void k_fused(
    const float* __restrict__ x,
    const float* __restrict__ c1w, const float* __restrict__ c1b,
    const float* __restrict__ c2w, const float* __restrict__ c2b,
    const float* __restrict__ fc1w, const ushort_t* __restrict__ fc1wb,
    const float* __restrict__ fc1b,
    const float* __restrict__ fc2w, const float* __restrict__ fc2b,
    const float* __restrict__ fc3w, const float* __restrict__ fc3b,
    const float* __restrict__ qw,
    const float* __restrict__ fc4w, const float* __restrict__ fc4b,
    float* __restrict__ out)
{
    // p1cl: plane g = ic>>3; within plane: ((y*16+x)*8 + (ic&7)) bf16.
    __shared__ __align__(16) ushort_t p1cl[8192];            // 16 KB
    __shared__ __align__(16) float p2[3136];                 // union: img(900) then p2
    __shared__ float h1s[128];
    __shared__ float h2s[64];
    __shared__ float fts[16];

    const int b = blockIdx.x, t = threadIdx.x;
    const int lane = t & 63, wv = t >> 6;

    for (int i = t; i < 4096; i += 256) ((uint_t*)p1cl)[i] = 0u;
    float* img = p2;                                          // 30x30 padded
    for (int i = t; i < 900; i += 256) img[i] = 0.f;
    __syncthreads();
    const float* xi = x + (size_t)b * 784;
    for (int i = t; i < 784; i += 256)
        img[(i/28 + 1)*30 + (i%28 + 1)] = xi[i];
    __syncthreads();

    // ---- conv1 (1->32) + ReLU + maxpool2 -> p1cl (bf16, plane = wv) ----
    {
        const int ocb1 = wv*8;
        float wk[8][9], bv[8];
        #pragma unroll
        for (int o = 0; o < 8; ++o) {
            bv[o] = c1b[ocb1 + o];
            #pragma unroll
            for (int k = 0; k < 9; ++k) wk[o][k] = c1w[(ocb1 + o)*9 + k];
        }
        #pragma unroll
        for (int ch = 0; ch < 4; ++ch) {
            int pos = ch*64 + lane;
            const bool act = pos < 196;
            if (!act) pos = 195;
            const int qy = pos / 14, qx = pos % 14;
            const float* ib = img + (2*qy)*30 + 2*qx;
            float v[4][4];
            #pragma unroll
            for (int rr = 0; rr < 4; ++rr) {
                const float2 a = *(const float2*)(ib + rr*30);
                const float2 c = *(const float2*)(ib + rr*30 + 2);
                v[rr][0]=a.x; v[rr][1]=a.y; v[rr][2]=c.x; v[rr][3]=c.y;
            }
            short8v pk;
            #pragma unroll
            for (int o = 0; o < 8; ++o) {
                float m = 0.f;                                // relu(max)==max(0,max)
                #pragma unroll
                for (int dy = 0; dy < 2; ++dy)
                #pragma unroll
                for (int dx = 0; dx < 2; ++dx) {
                    float acc = bv[o];
                    #pragma unroll
                    for (int ky = 0; ky < 3; ++ky)
                    #pragma unroll
                    for (int kx = 0; kx < 3; ++kx)
                        acc = fmaf(v[dy+ky][dx+kx], wk[o][ky*3+kx], acc);
                    m = fmaxf(m, acc);
                }
                pk[o] = (short)f2bf(m);
            }
            if (act)
                *(short8v*)&p1cl[wv*2048 + ((qy+1)*16 + (qx+1))*8] = pk;
        }
    }
    __syncthreads();                                          // img dead now

    // ---- conv2 (32->64) + ReLU + maxpool2 via MFMA -> p2 (verified r9) ----
    {
        const int ocb = wv*16;
        const int col = lane & 15, g = lane >> 4;
        const int oc  = ocb + col;
        short8v bfr[9];
        #pragma unroll
        for (int j = 0; j < 8; ++j) {
            const float* wp = c2w + ((size_t)oc*32 + g*8 + j)*9;
            #pragma unroll
            for (int s = 0; s < 9; ++s) bfr[s][j] = (short)f2bf(wp[s]);
        }
        const float bv = c2b[oc];
        #pragma unroll 1
        for (int mt = 0; mt < 13; ++mt) {
            int row = mt*16 + col; if (row > 195) row = 195;
            const int q  = row >> 2;
            const int py = q / 7, px = q - py*7;
            const int y0 = 2*py + ((row>>1)&1), x0 = 2*px + (row&1);
            const ushort_t* ap = &p1cl[g*2048 + (y0*16 + x0)*8];
            float4v c0 = {bv, bv, bv, bv};
            float4v c1 = {0.f, 0.f, 0.f, 0.f};
            c0 = __builtin_amdgcn_mfma_f32_16x16x32_bf16(*(const short8v*)(ap +   0), bfr[0], c0, 0, 0, 0);
            c1 = __builtin_amdgcn_mfma_f32_16x16x32_bf16(*(const short8v*)(ap +   8), bfr[1], c1, 0, 0, 0);
            c0 = __builtin_amdgcn_mfma_f32_16x16x32_bf16(*(const short8v*)(ap +  16), bfr[2], c0, 0, 0, 0);
            c1 = __builtin_amdgcn_mfma_f32_16x16x32_bf16(*(const short8v*)(ap + 128), bfr[3], c1, 0, 0, 0);
            c0 = __builtin_amdgcn_mfma_f32_16x16x32_bf16(*(const short8v*)(ap + 136), bfr[4], c0, 0, 0, 0);
            c1 = __builtin_amdgcn_mfma_f32_16x16x32_bf16(*(const short8v*)(ap + 144), bfr[5], c1, 0, 0, 0);
            c0 = __builtin_amdgcn_mfma_f32_16x16x32_bf16(*(const short8v*)(ap + 256), bfr[6], c0, 0, 0, 0);
            c1 = __builtin_amdgcn_mfma_f32_16x16x32_bf16(*(const short8v*)(ap + 264), bfr[7], c1, 0, 0, 0);
            c0 = __builtin_amdgcn_mfma_f32_16x16x32_bf16(*(const short8v*)(ap + 272), bfr[8], c0, 0, 0, 0);
            const int quad = mt*4 + g;
            if (quad < 49) {
                const float m0 = fmaxf(fmaxf(c0[0]+c1[0], c0[1]+c1[1]),
                                       fmaxf(c0[2]+c1[2], c0[3]+c1[3]));
                p2[oc*49 + quad] = fmaxf(m0, 0.f);
            }
        }
    }
    __syncthreads();

    // ---- fc1 (3136 -> 128) + ReLU ----
    if (fc1wb) {
        // bf16 weights from ws: half the L2 stream.
        for (int pass = 0; pass < 8; ++pass) {
            const int o = wv*32 + pass*4;
            const ushort_t* w0 = fc1wb + (size_t)o*3136;
            float a0=0.f, a1=0.f, a2=0.f, a3=0.f;
            for (int kb = 0; kb < 3072; kb += 256) {
                const int k = kb + lane*4;
                const float4 pv = *(const float4*)&p2[k];
                const ushort4v u0 = *(const ushort4v*)(w0 + k);
                const ushort4v u1 = *(const ushort4v*)(w0 + 3136 + k);
                const ushort4v u2 = *(const ushort4v*)(w0 + 6272 + k);
                const ushort4v u3 = *(const ushort4v*)(w0 + 9408 + k);
                a0 = fmaf(pv.x,bf2f(u0[0]),fmaf(pv.y,bf2f(u0[1]),fmaf(pv.z,bf2f(u0[2]),fmaf(pv.w,bf2f(u0[3]),a0))));
                a1 = fmaf(pv.x,bf2f(u1[0]),fmaf(pv.y,bf2f(u1[1]),fmaf(pv.z,bf2f(u1[2]),fmaf(pv.w,bf2f(u1[3]),a1))));
                a2 = fmaf(pv.x,bf2f(u2[0]),fmaf(pv.y,bf2f(u2[1]),fmaf(pv.z,bf2f(u2[2]),fmaf(pv.w,bf2f(u2[3]),a2))));
                a3 = fmaf(pv.x,bf2f(u3[0]),fmaf(pv.y,bf2f(u3[1]),fmaf(pv.z,bf2f(u3[2]),fmaf(pv.w,bf2f(u3[3]),a3))));
            }
            if (lane < 16) {                                  // tail 3072..3135
                const int k = 3072 + lane*4;
                const float4 pv = *(const float4*)&p2[k];
                const ushort4v u0 = *(const ushort4v*)(w0 + k);
                const ushort4v u1 = *(const ushort4v*)(w0 + 3136 + k);
                const ushort4v u2 = *(const ushort4v*)(w0 + 6272 + k);
                const ushort4v u3 = *(const ushort4v*)(w0 + 9408 + k);
                a0 = fmaf(pv.x,bf2f(u0[0]),fmaf(pv.y,bf2f(u0[1]),fmaf(pv.z,bf2f(u0[2]),fmaf(pv.w,bf2f(u0[3]),a0))));
                a1 = fmaf(pv.x,bf2f(u1[0]),fmaf(pv.y,bf2f(u1[1]),fmaf(pv.z,bf2f(u1[2]),fmaf(pv.w,bf2f(u1[3]),a1))));
                a2 = fmaf(pv.x,bf2f(u2[0]),fmaf(pv.y,bf2f(u2[1]),fmaf(pv.z,bf2f(u2[2]),fmaf(pv.w,bf2f(u2[3]),a2))));
                a3 = fmaf(pv.x,bf2f(u3[0]),fmaf(pv.y,bf2f(u3[1]),fmaf(pv.z,bf2f(u3[2]),fmaf(pv.w,bf2f(u3[3]),a3))));
            }
            #pragma unroll
            for (int s = 1; s < 64; s <<= 1) {
                a0 += __shfl_xor(a0, s);
                a1 += __shfl_xor(a1, s);
                a2 += __shfl_xor(a2, s);
                a3 += __shfl_xor(a3, s);
            }
            if (lane == ((o+0)&63)) h1s[o+0] = fmaxf(a0 + fc1b[o+0], 0.f);
            if (lane == ((o+1)&63)) h1s[o+1] = fmaxf(a1 + fc1b[o+1], 0.f);
            if (lane == ((o+2)&63)) h1s[o+2] = fmaxf(a2 + fc1b[o+2], 0.f);
            if (lane == ((o+3)&63)) h1s[o+3] = fmaxf(a3 + fc1b[o+3], 0.f);
        }
    } else {
        // fp32 fallback (round-9 verbatim), used only if ws too small.
        for (int pass = 0; pass < 8; ++pass) {
            const int o = wv*32 + pass*4;
            const float* w0 = fc1w + (size_t)o*3136;
            float a0=0.f, a1=0.f, a2=0.f, a3=0.f;
            for (int kb = 0; kb < 3072; kb += 256) {
                const int k = kb + lane*4;
                const float4 pv = *(const float4*)&p2[k];
                const float4 q0 = *(const float4*)(w0 + k);
                const float4 q1 = *(const float4*)(w0 + 3136 + k);
                const float4 q2 = *(const float4*)(w0 + 6272 + k);
                const float4 q3 = *(const float4*)(w0 + 9408 + k);
                a0 = fmaf(pv.x,q0.x,fmaf(pv.y,q0.y,fmaf(pv.z,q0.z,fmaf(pv.w,q0.w,a0))));
                a1 = fmaf(pv.x,q1.x,fmaf(pv.y,q1.y,fmaf(pv.z,q1.z,fmaf(pv.w,q1.w,a1))));
                a2 = fmaf(pv.x,q2.x,fmaf(pv.y,q2.y,fmaf(pv.z,q2.z,fmaf(pv.w,q2.w,a2))));
                a3 = fmaf(pv.x,q3.x,fmaf(pv.y,q3.y,fmaf(pv.z,q3.z,fmaf(pv.w,q3.w,a3))));
            }
            if (lane < 16) {
                const int k = 3072 + lane*4;
                const float4 pv = *(const float4*)&p2[k];
                const float4 q0 = *(const float4*)(w0 + k);
                const float4 q1 = *(const float4*)(w0 + 3136 + k);
                const float4 q2 = *(const float4*)(w0 + 6272 + k);
                const float4 q3 = *(const float4*)(w0 + 9408 + k);
                a0 = fmaf(pv.x,q0.x,fmaf(pv.y,q0.y,fmaf(pv.z,q0.z,fmaf(pv.w,q0.w,a0))));
                a1 = fmaf(pv.x,q1.x,fmaf(pv.y,q1.y,fmaf(pv.z,q1.z,fmaf(pv.w,q1.w,a1))));
                a2 = fmaf(pv.x,q2.x,fmaf(pv.y,q2.y,fmaf(pv.z,q2.z,fmaf(pv.w,q2.w,a2))));
                a3 = fmaf(pv.x,q3.x,fmaf(pv.y,q3.y,fmaf(pv.z,q3.z,fmaf(pv.w,q3.w,a3))));
            }
            #pragma unroll
            for (int s = 1; s < 64; s <<= 1) {
                a0 += __shfl_xor(a0, s);
                a1 += __shfl_xor(a1, s);
                a2 += __shfl_xor(a2, s);
                a3 += __shfl_xor(a3, s);
            }
            if (lane == ((o+0)&63)) h1s[o+0] = fmaxf(a0 + fc1b[o+0], 0.f);
            if (lane == ((o+1)&63)) h1s[o+1] = fmaxf(a1 + fc1b[o+1], 0.f);
            if (lane == ((o+2)&63)) h1s[o+2] = fmaxf(a2 + fc1b[o+2], 0.f);
            if (lane == ((o+3)&63)) h1s[o+3] = fmaxf(a3 + fc1b[o+3], 0.f);
        }
    }
    __syncthreads();

    // ---- fc2 (128 -> 64) + ReLU ----
    if (t < 64) {
        float a = fc2b[t];
        const float* wr = fc2w + t * 128;
        for (int k = 0; k < 128; ++k) a = fmaf(h1s[k], wr[k], a);
        h2s[t] = fmaxf(a, 0.f);
    }
    __syncthreads();

    // ---- fc3 (64 -> 16) + ReLU ----
    if (t < 16) {
        float a = fc3b[t];
        const float* wr = fc3w + t * 64;
        for (int k = 0; k < 64; ++k) a = fmaf(h2s[k], wr[k], a);
        fts[t] = fmaxf(a, 0.f);
    }
    __syncthreads();

    // ---- quantum circuit + fc4 + log_softmax: serial on thread 0 (verified) ----
    if (t == 0) {
        float feat[16];
        #pragma unroll
        for (int j = 0; j < 16; ++j) feat[j] = fts[j];

        float nrm2 = 0.f;
        #pragma unroll
        for (int j = 0; j < 16; ++j) nrm2 += feat[j]*feat[j];
        const float inv = 1.f / fmaxf(sqrtf(nrm2), 1e-12f);
        float ar[16], ai[16];
        #pragma unroll
        for (int j = 0; j < 16; ++j) { ar[j] = feat[j]*inv; ai[j] = 0.f; }

        #pragma unroll
        for (int layer = 0; layer < 2; ++layer) {
            #pragma unroll
            for (int q = 0; q < 4; ++q) {
                const float phi = qw[(layer*4 + q)*3 + 0];
                const float th  = qw[(layer*4 + q)*3 + 1];
                const float om  = qw[(layer*4 + q)*3 + 2];
                float st, ct; sincosf(0.5f*th, &st, &ct);
                float sa, ca; sincosf(0.5f*(phi + om), &sa, &ca); // ep = ca - i sa
                float sb, cb; sincosf(0.5f*(phi - om), &sb, &cb); // em = cb + i sb
                const float U00r =  ca*ct, U00i = -sa*ct;
                const float U01r = -cb*st, U01i = -sb*st;
                const float U10r =  cb*st, U10i = -sb*st;
                const float U11r =  ca*ct, U11i =  sa*ct;
                const int stride = 1 << (3 - q);
                #pragma unroll
                for (int i0 = 0; i0 < 16; ++i0) {
                    if (i0 & stride) continue;
                    const int i1 = i0 | stride;
                    const float r0 = ar[i0], m0 = ai[i0];
                    const float r1 = ar[i1], m1 = ai[i1];
                    ar[i0] = U00r*r0 - U00i*m0 + U01r*r1 - U01i*m1;
                    ai[i0] = U00r*m0 + U00i*r0 + U01r*m1 + U01i*r1;
                    ar[i1] = U10r*r0 - U10i*m0 + U11r*r1 - U11i*m1;
                    ai[i1] = U10r*m0 + U10i*r0 + U11r*m1 + U11i*r1;
                }
            }
            #pragma unroll
            for (int q = 0; q < 3; ++q) {   // CNOT control=q, target=q+1
                const int cbit = 1 << (3 - q), tbit = 1 << (2 - q);
                #pragma unroll
                for (int idx = 0; idx < 16; ++idx) {
                    if ((idx & cbit) && !(idx & tbit)) {
                        const int j = idx | tbit;
                        float tr = ar[idx]; ar[idx] = ar[j]; ar[j] = tr;
                        float ti = ai[idx]; ai[idx] = ai[j]; ai[j] = ti;
                    }
                }
            }
        }

        float qo[4];
        #pragma unroll
        for (int q = 0; q < 4; ++q) {
            const int pb = 1 << (3 - q);
            float s = 0.f;
            #pragma unroll
            for (int idx = 0; idx < 16; ++idx) {
                const float pv = ar[idx]*ar[idx] + ai[idx]*ai[idx];
                s += (idx & pb) ? -pv : pv;
            }
            qo[q] = s;
        }

        float z[10];
        float mx = -1e30f;
        #pragma unroll
        for (int o = 0; o < 10; ++o) {
            float a = fc4b[o];
            #pragma unroll
            for (int j = 0; j < 16; ++j) a = fmaf(feat[j], fc4w[o*20 + j], a);
            #pragma unroll
            for (int j = 0; j < 4;  ++j) a = fmaf(qo[j],  fc4w[o*20 + 16 + j], a);
            z[o] = a; mx = fmaxf(mx, a);
        }
        float se = 0.f;
        #pragma unroll
        for (int o = 0; o < 10; ++o) se += expf(z[o] - mx);
        const float lse = logf(se);
        #pragma unroll
        for (int o = 0; o < 10; ++o) out[(size_t)b*10 + o] = z[o] - mx - lse;
    }
}

// ---------------------------------------------------------------------------
extern "C" void kernel_launch(void* const* d_in, const int* in_sizes, int n_in,
                              void* d_out, int out_size, void* d_ws, size_t ws_size,
                              hipStream_t stream) {
    const float* x     = (const float*)d_in[0];
    const float* c1w   = (const float*)d_in[1];
    const float* c1b   = (const float*)d_in[2];
    const float* c2w   = (const float*)d_in[3];
    const float* c2b   = (const float*)d_in[4];
    const float* fc1w  = (const float*)d_in[5];
    const float* fc1b  = (const float*)d_in[6];
    const float* fc2w  = (const float*)d_in[7];
    const float* fc2b  = (const float*)d_in[8];
    const float* fc3w  = (const float*)d_in[9];
    const float* fc3b  = (const float*)d_in[10];
    const float* qwp   = (const float*)d_in[11];
    const float* fc4w  = (const float*)d_in[12];
    const float* fc4b  = (const float*)d_in[13];
    float* outp = (float*)d_out;

    const size_t WBYTES = (size_t)401408 * 2;                 // 128*3136 bf16
    ushort_t* wb = nullptr;
    if (ws_size >= WBYTES) {
        wb = (ushort_t*)d_ws;
        k_cvtw<<<196, 256, 0, stream>>>(fc1w, wb);
    }
    k_fused<<<1024, 256, 0, stream>>>(x, c1w, c1b, c2w, c2b, fc1w, wb, fc1b,
                                      fc2w, fc2b, fc3w, fc3b, qwp, fc4w, fc4b,
                                      outp);
}

// Round 11
// 103.517 us; speedup vs baseline: 1.5339x; 1.5339x over previous
//
#include <hip/hip_runtime.h>
#include <math.h>

typedef unsigned short ushort_t;
typedef unsigned int uint_t;
typedef __attribute__((ext_vector_type(8))) short short8v;       // 8 bf16 = 4 VGPR
typedef __attribute__((ext_vector_type(4))) float float4v;       // MFMA accum
typedef __attribute__((ext_vector_type(4))) unsigned short ushort4v; // 8B load

static __device__ __forceinline__ ushort_t f2bf(float f) {
    union { float f; uint_t u; } v; v.f = f;
    uint_t r = (v.u + 0x7FFFu + ((v.u >> 16) & 1u)) >> 16;       // RNE
    return (ushort_t)r;
}
static __device__ __forceinline__ float bf2f(ushort_t u) {
    union { uint_t u; float f; } v; v.u = ((uint_t)u) << 16;
    return v.f;
}

// ---------------------------------------------------------------------------
// K0: convert fc1w (128x3136 fp32) -> bf16 in ws. 196 blocks x 256 thr x 8.
// ---------------------------------------------------------------------------
__global__ __launch_bounds__(256) void k_cvtw(
    const float* __restrict__ w, ushort_t* __restrict__ o)
{
    const int i = (blockIdx.x*256 + threadIdx.x) * 8;
    const float4 a = *(const float4*)(w + i);
    const float4 b = *(const float4*)(w + i + 4);
    short8v pk;
    pk[0]=(short)f2bf(a.x); pk[1]=(short)f2bf(a.y);
    pk[2]=(short)f2bf(a.z); pk[3]=(short)f2bf(a.w);
    pk[4]=(short)f2bf(b.x); pk[5]=(short)f2bf(b.y);
    pk[6]=(short)f2bf(b.z); pk[7]=(short)f2bf(b.w);
    *(short8v*)(o + i) = pk;
}

// ---------------------------------------------------------------------------
// Shared device subroutines (inlined into both kernel variants).
// ---------------------------------------------------------------------------
static __device__ __forceinline__ void body_pre_fc1(
    const float* __restrict__ x,
    const float* __restrict__ c1w, const float* __restrict__ c1b,
    const float* __restrict__ c2w, const float* __restrict__ c2b,
    ushort_t* p1cl, float* p2, int b, int t, int lane, int wv)
{
    for (int i = t; i < 4096; i += 256) ((uint_t*)p1cl)[i] = 0u;
    float* img = p2;                                          // 30x30 padded
    for (int i = t; i < 900; i += 256) img[i] = 0.f;
    __syncthreads();
    const float* xi = x + (size_t)b * 784;
    for (int i = t; i < 784; i += 256)
        img[(i/28 + 1)*30 + (i%28 + 1)] = xi[i];
    __syncthreads();

    // ---- conv1 (1->32) + ReLU + maxpool2 -> p1cl (bf16, plane = wv) ----
    {
        const int ocb1 = wv*8;
        float wk[8][9], bv[8];
        #pragma unroll
        for (int o = 0; o < 8; ++o) {
            bv[o] = c1b[ocb1 + o];
            #pragma unroll
            for (int k = 0; k < 9; ++k) wk[o][k] = c1w[(ocb1 + o)*9 + k];
        }
        #pragma unroll
        for (int ch = 0; ch < 4; ++ch) {
            int pos = ch*64 + lane;
            const bool act = pos < 196;
            if (!act) pos = 195;
            const int qy = pos / 14, qx = pos % 14;
            const float* ib = img + (2*qy)*30 + 2*qx;
            float v[4][4];
            #pragma unroll
            for (int rr = 0; rr < 4; ++rr) {
                const float2 a = *(const float2*)(ib + rr*30);
                const float2 c = *(const float2*)(ib + rr*30 + 2);
                v[rr][0]=a.x; v[rr][1]=a.y; v[rr][2]=c.x; v[rr][3]=c.y;
            }
            short8v pk;
            #pragma unroll
            for (int o = 0; o < 8; ++o) {
                float m = 0.f;                                // relu(max)==max(0,max)
                #pragma unroll
                for (int dy = 0; dy < 2; ++dy)
                #pragma unroll
                for (int dx = 0; dx < 2; ++dx) {
                    float acc = bv[o];
                    #pragma unroll
                    for (int ky = 0; ky < 3; ++ky)
                    #pragma unroll
                    for (int kx = 0; kx < 3; ++kx)
                        acc = fmaf(v[dy+ky][dx+kx], wk[o][ky*3+kx], acc);
                    m = fmaxf(m, acc);
                }
                pk[o] = (short)f2bf(m);
            }
            if (act)
                *(short8v*)&p1cl[wv*2048 + ((qy+1)*16 + (qx+1))*8] = pk;
        }
    }
    __syncthreads();                                          // img dead now

    // ---- conv2 (32->64) + ReLU + maxpool2 via MFMA -> p2 ----
    {
        const int ocb = wv*16;
        const int col = lane & 15, g = lane >> 4;
        const int oc  = ocb + col;
        short8v bfr[9];
        #pragma unroll
        for (int j = 0; j < 8; ++j) {
            const float* wp = c2w + ((size_t)oc*32 + g*8 + j)*9;
            #pragma unroll
            for (int s = 0; s < 9; ++s) bfr[s][j] = (short)f2bf(wp[s]);
        }
        const float bv = c2b[oc];
        #pragma unroll 1
        for (int mt = 0; mt < 13; ++mt) {
            int row = mt*16 + col; if (row > 195) row = 195;
            const int q  = row >> 2;
            const int py = q / 7, px = q - py*7;
            const int y0 = 2*py + ((row>>1)&1), x0 = 2*px + (row&1);
            const ushort_t* ap = &p1cl[g*2048 + (y0*16 + x0)*8];
            float4v c0 = {bv, bv, bv, bv};
            float4v c1 = {0.f, 0.f, 0.f, 0.f};
            c0 = __builtin_amdgcn_mfma_f32_16x16x32_bf16(*(const short8v*)(ap +   0), bfr[0], c0, 0, 0, 0);
            c1 = __builtin_amdgcn_mfma_f32_16x16x32_bf16(*(const short8v*)(ap +   8), bfr[1], c1, 0, 0, 0);
            c0 = __builtin_amdgcn_mfma_f32_16x16x32_bf16(*(const short8v*)(ap +  16), bfr[2], c0, 0, 0, 0);
            c1 = __builtin_amdgcn_mfma_f32_16x16x32_bf16(*(const short8v*)(ap + 128), bfr[3], c1, 0, 0, 0);
            c0 = __builtin_amdgcn_mfma_f32_16x16x32_bf16(*(const short8v*)(ap + 136), bfr[4], c0, 0, 0, 0);
            c1 = __builtin_amdgcn_mfma_f32_16x16x32_bf16(*(const short8v*)(ap + 144), bfr[5], c1, 0, 0, 0);
            c0 = __builtin_amdgcn_mfma_f32_16x16x32_bf16(*(const short8v*)(ap + 256), bfr[6], c0, 0, 0, 0);
            c1 = __builtin_amdgcn_mfma_f32_16x16x32_bf16(*(const short8v*)(ap + 264), bfr[7], c1, 0, 0, 0);
            c0 = __builtin_amdgcn_mfma_f32_16x16x32_bf16(*(const short8v*)(ap + 272), bfr[8], c0, 0, 0, 0);
            const int quad = mt*4 + g;
            if (quad < 49) {
                const float m0 = fmaxf(fmaxf(c0[0]+c1[0], c0[1]+c1[1]),
                                       fmaxf(c0[2]+c1[2], c0[3]+c1[3]));
                p2[oc*49 + quad] = fmaxf(m0, 0.f);
            }
        }
    }
    __syncthreads();
}

static __device__ __forceinline__ void tail_post_fc1(
    const float* __restrict__ fc2w, const float* __restrict__ fc2b,
    const float* __restrict__ fc3w, const float* __restrict__ fc3b,
    const float* __restrict__ qw,
    const float* __restrict__ fc4w, const float* __restrict__ fc4b,
    float* __restrict__ out,
    float* h1s, float* h2s, float* fts, int b, int t)
{
    // ---- fc2 (128 -> 64) + ReLU ----
    if (t < 64) {
        float a = fc2b[t];
        const float* wr = fc2w + t * 128;
        for (int k = 0; k < 128; ++k) a = fmaf(h1s[k], wr[k], a);
        h2s[t] = fmaxf(a, 0.f);
    }
    __syncthreads();

    // ---- fc3 (64 -> 16) + ReLU ----
    if (t < 16) {
        float a = fc3b[t];
        const float* wr = fc3w + t * 64;
        for (int k = 0; k < 64; ++k) a = fmaf(h2s[k], wr[k], a);
        fts[t] = fmaxf(a, 0.f);
    }
    __syncthreads();

    // ---- quantum circuit + fc4 + log_softmax: serial on thread 0 ----
    if (t == 0) {
        float feat[16];
        #pragma unroll
        for (int j = 0; j < 16; ++j) feat[j] = fts[j];

        float nrm2 = 0.f;
        #pragma unroll
        for (int j = 0; j < 16; ++j) nrm2 += feat[j]*feat[j];
        const float inv = 1.f / fmaxf(sqrtf(nrm2), 1e-12f);
        float ar[16], ai[16];
        #pragma unroll
        for (int j = 0; j < 16; ++j) { ar[j] = feat[j]*inv; ai[j] = 0.f; }

        #pragma unroll
        for (int layer = 0; layer < 2; ++layer) {
            #pragma unroll
            for (int q = 0; q < 4; ++q) {
                const float phi = qw[(layer*4 + q)*3 + 0];
                const float th  = qw[(layer*4 + q)*3 + 1];
                const float om  = qw[(layer*4 + q)*3 + 2];
                float st, ct; sincosf(0.5f*th, &st, &ct);
                float sa, ca; sincosf(0.5f*(phi + om), &sa, &ca); // ep = ca - i sa
                float sb, cb; sincosf(0.5f*(phi - om), &sb, &cb); // em = cb + i sb
                const float U00r =  ca*ct, U00i = -sa*ct;
                const float U01r = -cb*st, U01i = -sb*st;
                const float U10r =  cb*st, U10i = -sb*st;
                const float U11r =  ca*ct, U11i =  sa*ct;
                const int stride = 1 << (3 - q);
                #pragma unroll
                for (int i0 = 0; i0 < 16; ++i0) {
                    if (i0 & stride) continue;
                    const int i1 = i0 | stride;
                    const float r0 = ar[i0], m0 = ai[i0];
                    const float r1 = ar[i1], m1 = ai[i1];
                    ar[i0] = U00r*r0 - U00i*m0 + U01r*r1 - U01i*m1;
                    ai[i0] = U00r*m0 + U00i*r0 + U01r*m1 + U01i*r1;
                    ar[i1] = U10r*r0 - U10i*m0 + U11r*r1 - U11i*m1;
                    ai[i1] = U10r*m0 + U10i*r0 + U11r*m1 + U11i*r1;
                }
            }
            #pragma unroll
            for (int q = 0; q < 3; ++q) {   // CNOT control=q, target=q+1
                const int cbit = 1 << (3 - q), tbit = 1 << (2 - q);
                #pragma unroll
                for (int idx = 0; idx < 16; ++idx) {
                    if ((idx & cbit) && !(idx & tbit)) {
                        const int j = idx | tbit;
                        float tr = ar[idx]; ar[idx] = ar[j]; ar[j] = tr;
                        float ti = ai[idx]; ai[idx] = ai[j]; ai[j] = ti;
                    }
                }
            }
        }

        float qo[4];
        #pragma unroll
        for (int q = 0; q < 4; ++q) {
            const int pb = 1 << (3 - q);
            float s = 0.f;
            #pragma unroll
            for (int idx = 0; idx < 16; ++idx) {
                const float pv = ar[idx]*ar[idx] + ai[idx]*ai[idx];
                s += (idx & pb) ? -pv : pv;
            }
            qo[q] = s;
        }

        float z[10];
        float mx = -1e30f;
        #pragma unroll
        for (int o = 0; o < 10; ++o) {
            float a = fc4b[o];
            #pragma unroll
            for (int j = 0; j < 16; ++j) a = fmaf(feat[j], fc4w[o*20 + j], a);
            #pragma unroll
            for (int j = 0; j < 4;  ++j) a = fmaf(qo[j],  fc4w[o*20 + 16 + j], a);
            z[o] = a; mx = fmaxf(mx, a);
        }
        float se = 0.f;
        #pragma unroll
        for (int o = 0; o < 10; ++o) se += expf(z[o] - mx);
        const float lse = logf(se);
        #pragma unroll
        for (int o = 0; o < 10; ++o) out[(size_t)b*10 + o] = z[o] - mx - lse;
    }
}

// ---------------------------------------------------------------------------
// Variant B (primary): fc1 reads bf16 weights from ws. No fp32 fc1 code.
// ---------------------------------------------------------------------------
__global__ __launch_bounds__(256) void k_fused_b(
    const float* __restrict__ x,
    const float* __restrict__ c1w, const float* __restrict__ c1b,
    const float* __restrict__ c2w, const float* __restrict__ c2b,
    const ushort_t* __restrict__ fc1wb, const float* __restrict__ fc1b,
    const float* __restrict__ fc2w, const float* __restrict__ fc2b,
    const float* __restrict__ fc3w, const float* __restrict__ fc3b,
    const float* __restrict__ qw,
    const float* __restrict__ fc4w, const float* __restrict__ fc4b,
    float* __restrict__ out)
{
    __shared__ __align__(16) ushort_t p1cl[8192];            // 16 KB
    __shared__ __align__(16) float p2[3136];                 // union: img then p2
    __shared__ float h1s[128];
    __shared__ float h2s[64];
    __shared__ float fts[16];

    const int b = blockIdx.x, t = threadIdx.x;
    const int lane = t & 63, wv = t >> 6;

    body_pre_fc1(x, c1w, c1b, c2w, c2b, p1cl, p2, b, t, lane, wv);

    // ---- fc1 (3136 -> 128) + ReLU, bf16 weights ----
    for (int pass = 0; pass < 8; ++pass) {
        const int o = wv*32 + pass*4;
        const ushort_t* w0 = fc1wb + (size_t)o*3136;
        float a0=0.f, a1=0.f, a2=0.f, a3=0.f;
        #pragma unroll 2
        for (int kb = 0; kb < 3072; kb += 256) {
            const int k = kb + lane*4;
            const float4 pv = *(const float4*)&p2[k];
            const ushort4v u0 = *(const ushort4v*)(w0 + k);
            const ushort4v u1 = *(const ushort4v*)(w0 + 3136 + k);
            const ushort4v u2 = *(const ushort4v*)(w0 + 6272 + k);
            const ushort4v u3 = *(const ushort4v*)(w0 + 9408 + k);
            a0 = fmaf(pv.x,bf2f(u0[0]),fmaf(pv.y,bf2f(u0[1]),fmaf(pv.z,bf2f(u0[2]),fmaf(pv.w,bf2f(u0[3]),a0))));
            a1 = fmaf(pv.x,bf2f(u1[0]),fmaf(pv.y,bf2f(u1[1]),fmaf(pv.z,bf2f(u1[2]),fmaf(pv.w,bf2f(u1[3]),a1))));
            a2 = fmaf(pv.x,bf2f(u2[0]),fmaf(pv.y,bf2f(u2[1]),fmaf(pv.z,bf2f(u2[2]),fmaf(pv.w,bf2f(u2[3]),a2))));
            a3 = fmaf(pv.x,bf2f(u3[0]),fmaf(pv.y,bf2f(u3[1]),fmaf(pv.z,bf2f(u3[2]),fmaf(pv.w,bf2f(u3[3]),a3))));
        }
        if (lane < 16) {                                      // tail 3072..3135
            const int k = 3072 + lane*4;
            const float4 pv = *(const float4*)&p2[k];
            const ushort4v u0 = *(const ushort4v*)(w0 + k);
            const ushort4v u1 = *(const ushort4v*)(w0 + 3136 + k);
            const ushort4v u2 = *(const ushort4v*)(w0 + 6272 + k);
            const ushort4v u3 = *(const ushort4v*)(w0 + 9408 + k);
            a0 = fmaf(pv.x,bf2f(u0[0]),fmaf(pv.y,bf2f(u0[1]),fmaf(pv.z,bf2f(u0[2]),fmaf(pv.w,bf2f(u0[3]),a0))));
            a1 = fmaf(pv.x,bf2f(u1[0]),fmaf(pv.y,bf2f(u1[1]),fmaf(pv.z,bf2f(u1[2]),fmaf(pv.w,bf2f(u1[3]),a1))));
            a2 = fmaf(pv.x,bf2f(u2[0]),fmaf(pv.y,bf2f(u2[1]),fmaf(pv.z,bf2f(u2[2]),fmaf(pv.w,bf2f(u2[3]),a2))));
            a3 = fmaf(pv.x,bf2f(u3[0]),fmaf(pv.y,bf2f(u3[1]),fmaf(pv.z,bf2f(u3[2]),fmaf(pv.w,bf2f(u3[3]),a3))));
        }
        #pragma unroll
        for (int s = 1; s < 64; s <<= 1) {
            a0 += __shfl_xor(a0, s);
            a1 += __shfl_xor(a1, s);
            a2 += __shfl_xor(a2, s);
            a3 += __shfl_xor(a3, s);
        }
        if (lane == ((o+0)&63)) h1s[o+0] = fmaxf(a0 + fc1b[o+0], 0.f);
        if (lane == ((o+1)&63)) h1s[o+1] = fmaxf(a1 + fc1b[o+1], 0.f);
        if (lane == ((o+2)&63)) h1s[o+2] = fmaxf(a2 + fc1b[o+2], 0.f);
        if (lane == ((o+3)&63)) h1s[o+3] = fmaxf(a3 + fc1b[o+3], 0.f);
    }
    __syncthreads();

    tail_post_fc1(fc2w, fc2b, fc3w, fc3b, qw, fc4w, fc4b, out, h1s, h2s, fts, b, t);
}

// ---------------------------------------------------------------------------
// Variant A (fallback, round-9 verbatim): fp32 fc1 weights.
// ---------------------------------------------------------------------------
__global__ __launch_bounds__(256) void k_fused_a(
    const float* __restrict__ x,
    const float* __restrict__ c1w, const float* __restrict__ c1b,
    const float* __restrict__ c2w, const float* __restrict__ c2b,
    const float* __restrict__ fc1w, const float* __restrict__ fc1b,
    const float* __restrict__ fc2w, const float* __restrict__ fc2b,
    const float* __restrict__ fc3w, const float* __restrict__ fc3b,
    const float* __restrict__ qw,
    const float* __restrict__ fc4w, const float* __restrict__ fc4b,
    float* __restrict__ out)
{
    __shared__ __align__(16) ushort_t p1cl[8192];
    __shared__ __align__(16) float p2[3136];
    __shared__ float h1s[128];
    __shared__ float h2s[64];
    __shared__ float fts[16];

    const int b = blockIdx.x, t = threadIdx.x;
    const int lane = t & 63, wv = t >> 6;

    body_pre_fc1(x, c1w, c1b, c2w, c2b, p1cl, p2, b, t, lane, wv);

    for (int pass = 0; pass < 8; ++pass) {
        const int o = wv*32 + pass*4;
        const float* w0 = fc1w + (size_t)o*3136;
        float a0=0.f, a1=0.f, a2=0.f, a3=0.f;
        for (int kb = 0; kb < 3072; kb += 256) {
            const int k = kb + lane*4;
            const float4 pv = *(const float4*)&p2[k];
            const float4 q0 = *(const float4*)(w0 + k);
            const float4 q1 = *(const float4*)(w0 + 3136 + k);
            const float4 q2 = *(const float4*)(w0 + 6272 + k);
            const float4 q3 = *(const float4*)(w0 + 9408 + k);
            a0 = fmaf(pv.x,q0.x,fmaf(pv.y,q0.y,fmaf(pv.z,q0.z,fmaf(pv.w,q0.w,a0))));
            a1 = fmaf(pv.x,q1.x,fmaf(pv.y,q1.y,fmaf(pv.z,q1.z,fmaf(pv.w,q1.w,a1))));
            a2 = fmaf(pv.x,q2.x,fmaf(pv.y,q2.y,fmaf(pv.z,q2.z,fmaf(pv.w,q2.w,a2))));
            a3 = fmaf(pv.x,q3.x,fmaf(pv.y,q3.y,fmaf(pv.z,q3.z,fmaf(pv.w,q3.w,a3))));
        }
        if (lane < 16) {
            const int k = 3072 + lane*4;
            const float4 pv = *(const float4*)&p2[k];
            const float4 q0 = *(const float4*)(w0 + k);
            const float4 q1 = *(const float4*)(w0 + 3136 + k);
            const float4 q2 = *(const float4*)(w0 + 6272 + k);
            const float4 q3 = *(const float4*)(w0 + 9408 + k);
            a0 = fmaf(pv.x,q0.x,fmaf(pv.y,q0.y,fmaf(pv.z,q0.z,fmaf(pv.w,q0.w,a0))));
            a1 = fmaf(pv.x,q1.x,fmaf(pv.y,q1.y,fmaf(pv.z,q1.z,fmaf(pv.w,q1.w,a1))));
            a2 = fmaf(pv.x,q2.x,fmaf(pv.y,q2.y,fmaf(pv.z,q2.z,fmaf(pv.w,q2.w,a2))));
            a3 = fmaf(pv.x,q3.x,fmaf(pv.y,q3.y,fmaf(pv.z,q3.z,fmaf(pv.w,q3.w,a3))));
        }
        #pragma unroll
        for (int s = 1; s < 64; s <<= 1) {
            a0 += __shfl_xor(a0, s);
            a1 += __shfl_xor(a1, s);
            a2 += __shfl_xor(a2, s);
            a3 += __shfl_xor(a3, s);
        }
        if (lane == ((o+0)&63)) h1s[o+0] = fmaxf(a0 + fc1b[o+0], 0.f);
        if (lane == ((o+1)&63)) h1s[o+1] = fmaxf(a1 + fc1b[o+1], 0.f);
        if (lane == ((o+2)&63)) h1s[o+2] = fmaxf(a2 + fc1b[o+2], 0.f);
        if (lane == ((o+3)&63)) h1s[o+3] = fmaxf(a3 + fc1b[o+3], 0.f);
    }
    __syncthreads();

    tail_post_fc1(fc2w, fc2b, fc3w, fc3b, qw, fc4w, fc4b, out, h1s, h2s, fts, b, t);
}

// ---------------------------------------------------------------------------
extern "C" void kernel_launch(void* const* d_in, const int* in_sizes, int n_in,
                              void* d_out, int out_size, void* d_ws, size_t ws_size,
                              hipStream_t stream) {
    const float* x     = (const float*)d_in[0];
    const float* c1w   = (const float*)d_in[1];
    const float* c1b   = (const float*)d_in[2];
    const float* c2w   = (const float*)d_in[3];
    const float* c2b   = (const float*)d_in[4];
    const float* fc1w  = (const float*)d_in[5];
    const float* fc1b  = (const float*)d_in[6];
    const float* fc2w  = (const float*)d_in[7];
    const float* fc2b  = (const float*)d_in[8];
    const float* fc3w  = (const float*)d_in[9];
    const float* fc3b  = (const float*)d_in[10];
    const float* qwp   = (const float*)d_in[11];
    const float* fc4w  = (const float*)d_in[12];
    const float* fc4b  = (const float*)d_in[13];
    float* outp = (float*)d_out;

    const size_t WBYTES = (size_t)401408 * 2;                 // 128*3136 bf16
    if (ws_size >= WBYTES) {
        ushort_t* wb = (ushort_t*)d_ws;
        k_cvtw<<<196, 256, 0, stream>>>(fc1w, wb);
        k_fused_b<<<1024, 256, 0, stream>>>(x, c1w, c1b, c2w, c2b, wb, fc1b,
                                            fc2w, fc2b, fc3w, fc3b, qwp,
                                            fc4w, fc4b, outp);
    } else {
        k_fused_a<<<1024, 256, 0, stream>>>(x, c1w, c1b, c2w, c2b, fc1w, fc1b,
                                            fc2w, fc2b, fc3w, fc3b, qwp,
                                            fc4w, fc4b, outp);
    }
}